// Round 19
// baseline (15868.582 us; speedup 1.0000x reference)
//
#include <hip/hip_runtime.h>

#define T_STEPS 512
#define BATCH 64
#define DIM 1024
#define HID 1024
#define NLAYER 2
#define XP_STEP (64*5*1024)   // packed-xp elements per time step (64 blocks x 5 planes x 1024)
#define FSTRIDE 4             // flag stride in u32 (16B): 4 flags per 64B line
#define MFMA_B16 __builtin_amdgcn_mfma_f32_16x16x32_bf16

typedef __attribute__((ext_vector_type(8))) short bf16x8;
typedef __attribute__((ext_vector_type(4))) float f32x4;
typedef unsigned short u16;
typedef unsigned int u32;
typedef unsigned long long u64;

__device__ inline float bf2f(u16 u){ u32 v=((u32)u)<<16; float f; __builtin_memcpy(&f,&v,4); return f; }
__device__ inline u16 f2bf(float f){ u32 u; __builtin_memcpy(&u,&f,4); u = (u + 0x7fffu + ((u>>16)&1u))>>16; return (u16)u; }
__device__ inline float sigm(float x){ return 1.f/(1.f+__expf(-x)); }

__device__ inline u32 ld_cc(const u32* p){ return __hip_atomic_load(p, __ATOMIC_RELAXED, __HIP_MEMORY_SCOPE_SYSTEM); }
__device__ inline void st_cc(u32* p, u32 v){ __hip_atomic_store(p, v, __ATOMIC_RELAXED, __HIP_MEMORY_SCOPE_SYSTEM); }

// 8 wide coherent loads (512B span), one addr + imm offsets, no wait (caller waits).
__device__ __forceinline__ void ld8_sys(const u16* p, bf16x8* f){
  asm volatile(
    "global_load_dwordx4 %0, %8, off sc0 sc1\n\t"
    "global_load_dwordx4 %1, %8, off offset:64 sc0 sc1\n\t"
    "global_load_dwordx4 %2, %8, off offset:128 sc0 sc1\n\t"
    "global_load_dwordx4 %3, %8, off offset:192 sc0 sc1\n\t"
    "global_load_dwordx4 %4, %8, off offset:256 sc0 sc1\n\t"
    "global_load_dwordx4 %5, %8, off offset:320 sc0 sc1\n\t"
    "global_load_dwordx4 %6, %8, off offset:384 sc0 sc1\n\t"
    "global_load_dwordx4 %7, %8, off offset:448 sc0 sc1"
    : "=&v"(f[0]),"=&v"(f[1]),"=&v"(f[2]),"=&v"(f[3]),
      "=&v"(f[4]),"=&v"(f[5]),"=&v"(f[6]),"=&v"(f[7])
    : "v"(p)
    : "memory");
}
#define WAITV(S) do{ asm volatile("s_waitcnt vmcnt(" S ")" ::: "memory"); __builtin_amdgcn_sched_barrier(0); }while(0)

// Wait until all 16 producers of group GIDX have flag >= THR (cached ballot mask).
// NOTE: a spinning ballot only OVER-drains vmcnt, so counted WAITVs stay safe.
#define WG(FL, THR, GIDX, READY) do{ \
    u64 need_ = 0xFFFFull << ((GIDX)*16); \
    while(((READY) & need_) != need_){ \
      u32 v_ = ld_cc((FL) + (size_t)lane*FSTRIDE); \
      (READY) = __ballot(v_ >= (u32)(THR)); \
    } }while(0)

// ---------------- fp32 -> bf16 cast ----------------
__global__ void cast_f2bf(const float* __restrict__ src, u16* __restrict__ dst, int n4){
  int i = blockIdx.x*blockDim.x + threadIdx.x;
  int stride = gridDim.x*blockDim.x;
  for(; i<n4; i+=stride){
    float4 v = ((const float4*)src)[i];
    ushort4 o; o.x=f2bf(v.x); o.y=f2bf(v.y); o.z=f2bf(v.z); o.w=f2bf(v.w);
    ((ushort4*)dst)[i]=o;
  }
}

// ---------------- transpose + cast: src fp32 [R][C] -> dst bf16 [C][R] ----------------
__global__ void transpose_cast(const float* __restrict__ src, u16* __restrict__ dst, int R, int C){
  __shared__ float tile[32][33];
  int c0 = blockIdx.x*32, r0 = blockIdx.y*32;
  int tx = threadIdx.x, ty = threadIdx.y;
  for(int i=ty;i<32;i+=8) tile[i][tx] = src[(size_t)(r0+i)*C + c0+tx];
  __syncthreads();
  for(int i=ty;i<32;i+=8) dst[(size_t)(c0+i)*R + r0+tx] = f2bf(tile[tx][i]);
}

// ---------------- bias2 = bhh @ Wg + bg ----------------
__global__ void bias2_kernel(const u16* __restrict__ Wg_t, const float* __restrict__ bhh,
                             const float* __restrict__ bg, float* __restrict__ bias2){
  int w = (blockIdx.x*blockDim.x + threadIdx.x)>>6;
  int lane = threadIdx.x&63;
  if(w >= 3*HID) return;
  float s=0.f;
  for(int j=lane;j<HID;j+=64) s += bf2f(Wg_t[(size_t)w*HID + j]) * bhh[j];
  for(int off=32;off;off>>=1) s += __shfl_down(s, off);
  if(lane==0) bias2[w] = s + bg[w];
}

// ---------------- bf16 GEMM: C = A @ Bt^T + bias ----------------
// MODE 0: plain write. MODE 1: packed [t][cj][p][b][16c]. MODE 2: packed += (A from plane 1).
template<int MODE>
__launch_bounds__(256)
__global__ void gemm_bt(const u16* __restrict__ A, const u16* __restrict__ Bt,
                        const float* __restrict__ bias, u16* __restrict__ Cmat,
                        int M, int N, int K, u16* packed){
  __shared__ __align__(16) u16 As[128*32];
  __shared__ __align__(16) u16 Bs[128*32];
  const int tid=threadIdx.x, lane=tid&63, wave=tid>>6;
  const size_t m0 = (size_t)blockIdx.y*128, n0=(size_t)blockIdx.x*128;
  const int wr=wave>>1, wc=wave&1, fr=lane&15, fq=lane>>4;
  f32x4 acc[4][4];
  for(int m=0;m<4;m++) for(int n=0;n<4;n++) acc[m][n]=(f32x4){0.f,0.f,0.f,0.f};
  const int nk = K>>5;
  for(int kt=0;kt<nk;kt++){
    __syncthreads();
    for(int j=0;j<2;j++){
      int c = tid + j*256; int row=c>>2; int ko=(c&3)*8;
      if constexpr (MODE==2){
        size_t g = m0+row; int kc = kt*32+ko;
        size_t addr = (((g>>6)*64 + (size_t)(kc>>4))*5 + 1)*1024 + (g&63)*16 + (kc&15);
        *(int4*)&As[row*32+ko] = *(const int4*)&A[addr];
      } else {
        *(int4*)&As[row*32+ko] = *(const int4*)&A[(m0+row)*K + kt*32+ko];
      }
      *(int4*)&Bs[row*32+ko] = *(const int4*)&Bt[(n0+row)*K + kt*32+ko];
    }
    __syncthreads();
    bf16x8 af[4], bfv[4];
    for(int m=0;m<4;m++) af[m]=*(const bf16x8*)&As[(wr*64+m*16+fr)*32 + fq*8];
    for(int n=0;n<4;n++) bfv[n]=*(const bf16x8*)&Bs[(wc*64+n*16+fr)*32 + fq*8];
    for(int m=0;m<4;m++)
      for(int n=0;n<4;n++)
        acc[m][n]=MFMA_B16(af[m],bfv[n],acc[m][n],0,0,0);
  }
  for(int n=0;n<4;n++){
    size_t colg = n0 + wc*64+n*16+fr;
    float bv = bias[colg];
    for(int m=0;m<4;m++){
      for(int r=0;r<4;r++){
        size_t rowg = m0 + wr*64+m*16+fq*4+r;
        float v = acc[m][n][r]+bv;
        if constexpr (MODE==0){
          Cmat[rowg*N + colg] = f2bf(v);
        } else if constexpr (MODE==1){
          size_t p = colg>>10, pc = colg&1023;
          size_t t = rowg>>6, b = rowg&63, cj = pc>>4, c = pc&15;
          packed[((t*64+cj)*5 + p)*1024 + b*16 + c] = f2bf(v);
        } else {
          size_t pp = colg>>10, pc = colg&1023;
          size_t t = rowg>>6, b = rowg&63, cj = pc>>4, c = pc&15;
          u16* dst = packed + ((t*64+cj)*5 + (2+pp))*1024 + b*16 + c;
          *dst = f2bf(v + bf2f(*dst));
        }
      }
    }
  }
}

// ---------------- persistent recurrent kernel: barrier-free dataflow ----------------
// 64 blocks x 256 threads. Block cj owns cols [16cj,16cj+16); wave w owns rows
// 16*((w+cj)&3). Per-producer flags + 4-group chunked consumption (cached
// ballot). m/h parity double-buffered. xp via global->register scalar loads.
// r19: flags packed at 16B stride (was 128B) — wave-poll touches 16 L3 lines
// instead of 64; 4 producers share a 64B line (plain stores, no RMW serialization).
__launch_bounds__(256, 1)
__global__ void mlstm_rec(const u16* __restrict__ xp_pack,
   const u16* __restrict__ Wmh_t, const u16* __restrict__ Whh_t, const u16* __restrict__ WhhG_t,
   const float* __restrict__ bmh, const float* __restrict__ bhh,
   u16* h_buf, float* c_buf, u16* m_buf,
   u16* seq_bf, float* seq_f32, float* hn, float* cn, u32* flags, int is_first)
{
  __shared__ __align__(16) u16 wlds[64*1024];   // 128 KiB swizzled Whh|WhhG
  const int tid=threadIdx.x, lane=tid&63, wave=tid>>6;
  const int cj = blockIdx.x, cb = cj*16;
  const int rowbase = ((wave + cj) & 3) * 16;
  const int fr=lane&15, fq=lane>>4;
  const int col = cb+fr;
  const u32 a_off = (u32)(rowbase+fr)*HID + fq*8;
  const size_t w_off = (size_t)col*HID + fq*8;
  const u32 swz = ((u32)(fr&7))<<4;
  const int grot = cj&3;
  const int G0=(0+grot)&3, G1=(1+grot)&3, G2=(2+grot)&3, G3=(3+grot)&3;
  u32* mfl = flags;                  // mflag[p] at +p*FSTRIDE
  u32* hfl = flags + 1024;           // hflag[p] at +1024+p*FSTRIDE (separate 4KB page)
  const size_t BH = (size_t)BATCH*HID;

  // ---- stage Whh|WhhG into swizzled LDS (once): 8192 x 16B chunks
  for(int it=0; it<32; ++it){
    int chunk = it*256 + tid;
    int cl = chunk >> 7;
    int kb = (chunk & 127) * 16;
    const u16* src;
    if(cl < 16) src = Whh_t + (size_t)(cb+cl)*HID;
    else { int g=(cl-16)>>4, j=cl&15; src = WhhG_t + (size_t)(g*HID + cb + j)*HID; }
    u32 dst = ((u32)cl*2048 + (u32)kb) ^ (((u32)cl&7)<<4);
    *(int4*)((char*)wlds + dst) = *(const int4*)((const char*)src + kb);
  }

  // ---- Wmh fragments into regs, PERMUTED so wmh[8g+j] pairs with kt=8*G(g)+j
  bf16x8 wmh[32];
  {
    const int gtab[4] = {G0,G1,G2,G3};
    #pragma unroll
    for(int g=0; g<4; g++){
      int gg = gtab[g];
      #pragma unroll
      for(int j=0;j<8;j++)
        wmh[8*g+j] = *(const bf16x8*)(Wmh_t + w_off + (size_t)(8*gg+j)*32);
    }
  }

  float c_reg[4], h4[4];
  if(is_first){ for(int r=0;r<4;r++) c_reg[r]=0.f; }
  else { for(int r=0;r<4;r++) c_reg[r]=c_buf[(size_t)(rowbase+fq*4+r)*HID+col]; }
  for(int r=0;r<4;r++) h4[r]=0.f;

  const float bmh_c=bmh[col], bhh_c=bhh[col];

  // per-thread xp base for step 0: chunk cj + [p*1024 + (rowbase+fq*4+r)*16 + fr]
  const u16* xb = xp_pack + (size_t)cj*5120 + (size_t)(rowbase+fq*4)*16 + fr;
  u32 xmi_c[4];
  #pragma unroll
  for(int r=0;r<4;r++) xmi_c[r] = xb[r*16];

  __syncthreads();

  #define MFMA8A(H, W0) do{ \
    a0=MFMA_B16((H)[0],wmh[(W0)+0],a0,0,0,0); a1=MFMA_B16((H)[1],wmh[(W0)+1],a1,0,0,0); \
    a0=MFMA_B16((H)[2],wmh[(W0)+2],a0,0,0,0); a1=MFMA_B16((H)[3],wmh[(W0)+3],a1,0,0,0); \
    a0=MFMA_B16((H)[4],wmh[(W0)+4],a0,0,0,0); a1=MFMA_B16((H)[5],wmh[(W0)+5],a1,0,0,0); \
    a0=MFMA_B16((H)[6],wmh[(W0)+6],a0,0,0,0); a1=MFMA_B16((H)[7],wmh[(W0)+7],a1,0,0,0); \
  }while(0)

  #define MFMA8B(MF, GG) do{ \
    _Pragma("unroll") \
    for(int j=0;j<8;j++){ \
      u32 kb = ((u32)(GG)*8u + (u32)j)*64u + (u32)fq*16u; \
      bf16x8 w0=*(const bf16x8*)(wb + ((((u32)(   fr))*2048 + kb) ^ swz)); \
      bf16x8 w1=*(const bf16x8*)(wb + ((((u32)(16+fr))*2048 + kb) ^ swz)); \
      bf16x8 w2=*(const bf16x8*)(wb + ((((u32)(32+fr))*2048 + kb) ^ swz)); \
      bf16x8 w3=*(const bf16x8*)(wb + ((((u32)(48+fr))*2048 + kb) ^ swz)); \
      ag =MFMA_B16((MF)[j],w0,ag ,0,0,0); aiv=MFMA_B16((MF)[j],w1,aiv,0,0,0); \
      aov=MFMA_B16((MF)[j],w2,aov,0,0,0); afv=MFMA_B16((MF)[j],w3,afv,0,0,0); \
    } }while(0)

  const char* wb = (const char*)wlds;

  for(int t=0;t<T_STEPS;t++){
    // ================= Stage A: m = xmi * (h @ Wmh + bmh) =================
    const u16* h_r = h_buf + (size_t)(t&1)*BH + a_off;
    u64 hready = 0;
    bf16x8 hA[8], hB[8];
    f32x4 a0={0.f,0.f,0.f,0.f}, a1={0.f,0.f,0.f,0.f};
    WG(hfl, t, G0, hready); ld8_sys(h_r + G0*256, hA);
    WG(hfl, t, G1, hready); ld8_sys(h_r + G1*256, hB);
    WAITV("8");  MFMA8A(hA, 0);
    WG(hfl, t, G2, hready); ld8_sys(h_r + G2*256, hA);
    WAITV("8");  MFMA8A(hB, 8);
    WG(hfl, t, G3, hready); ld8_sys(h_r + G3*256, hB);
    WAITV("8");  MFMA8A(hA, 16);
    WAITV("0");  MFMA8A(hB, 24);
    {
      u16* m_w = m_buf + (size_t)(t&1)*BH;
      #pragma unroll
      for(int r=0;r<4;r++){
        int b = rowbase+fq*4+r;
        float xmiv = bf2f((u16)xmi_c[r]);
        u32 my=(u32)f2bf(xmiv*(a0[r]+a1[r]+bmh_c));
        u32 ot=(u32)__shfl_xor((int)my,1);
        if((lane&1)==0) st_cc((u32*)(m_w + (size_t)b*HID + col), my|(ot<<16));
      }
    }
    __syncthreads();            // implicit per-wave vmcnt(0) drains m stores (+prev seq)
    if(tid==0) st_cc(&mfl[(size_t)cj*FSTRIDE], (u32)(t+1));

    // ================= Stage B: [g|i|o|f] = m @ [Whh|WhhG]_lds =================
    const u16* m_r = m_buf + (size_t)(t&1)*BH + a_off;
    u64 mready = 0;
    bf16x8 mA[8], mB[8];
    f32x4 ag={0.f,0.f,0.f,0.f}, aiv={0.f,0.f,0.f,0.f}, aov={0.f,0.f,0.f,0.f}, afv={0.f,0.f,0.f,0.f};
    WG(mfl, t+1, G0, mready); ld8_sys(m_r + G0*256, mA);
    WG(mfl, t+1, G1, mready); ld8_sys(m_r + G1*256, mB);
    // xp scalar loads: 16 gate values (step t) + 4 xmi (step t+1) — 20 VMEM ops
    const u16* xbn = (t+1<T_STEPS)? (xb+XP_STEP) : xb;
    u32 xhi_[4],xgi_[4],xgo_[4],xgf_[4],xmi_n[4];
    #pragma unroll
    for(int r=0;r<4;r++){ xhi_[r]=xb[1024+r*16]; xgi_[r]=xb[2048+r*16];
                          xgo_[r]=xb[3072+r*16]; xgf_[r]=xb[4096+r*16]; }
    #pragma unroll
    for(int r=0;r<4;r++){ xmi_n[r]=xbn[r*16]; }
    // queue: G0(8) G1(8) scalars(20) | +G2(8) | +G3(8)
    WAITV("28"); MFMA8B(mA, G0);                      // drains G0
    WG(mfl, t+1, G2, mready); ld8_sys(m_r + G2*256, mA);
    WAITV("28"); MFMA8B(mB, G1);                      // drains G1
    WG(mfl, t+1, G3, mready); ld8_sys(m_r + G3*256, mB);
    WAITV("8");  MFMA8B(mA, G2);                      // drains scalars + G2
    WAITV("0");  MFMA8B(mB, G3);                      // drains G3
    // gates + state update; h stores FIRST (gate the flag), seq AFTER the post
    {
      u16* h_w = h_buf + (size_t)((t+1)&1)*BH;
      #pragma unroll
      for(int r=0;r<4;r++){
        int b=rowbase+fq*4+r;
        float g  = ag[r]+bhh_c+bf2f((u16)xhi_[r]);
        float iv = sigm(aiv[r]+bf2f((u16)xgi_[r]));
        float ov = sigm(aov[r]+bf2f((u16)xgo_[r]));
        float fv = sigm(afv[r]+bf2f((u16)xgf_[r]));
        c_reg[r]=fv*c_reg[r]+iv*tanhf(g);
        h4[r]=tanhf(c_reg[r])*ov;
        u32 my=(u32)f2bf(h4[r]);
        u32 ot=(u32)__shfl_xor((int)my,1);
        if((lane&1)==0) st_cc((u32*)(h_w + (size_t)b*HID + col), my|(ot<<16));
      }
    }
    __syncthreads();            // implicit per-wave vmcnt(0) drains h stores ONLY
    if(tid==0) st_cc(&hfl[(size_t)cj*FSTRIDE], (u32)(t+1));
    // seq output stores AFTER the flag post — retire during next stage A
    {
      const size_t tb=(size_t)t*BH;
      #pragma unroll
      for(int r=0;r<4;r++){
        int b=rowbase+fq*4+r;
        if(seq_bf) seq_bf[tb+(size_t)b*HID+col]=f2bf(h4[r]);
        else       seq_f32[tb+(size_t)b*HID+col]=h4[r];
      }
    }
    #pragma unroll
    for(int r=0;r<4;r++) xmi_c[r]=xmi_n[r];
    xb = xbn;
  }
  // epilogue: hn, cn (seq written every step)
  for(int r=0;r<4;r++){
    int row=rowbase+fq*4+r;
    hn[(size_t)row*HID+col]=h4[r];
    cn[(size_t)row*HID+col]=c_reg[r];
    if(is_first) c_buf[(size_t)row*HID+col]=c_reg[r];
  }
}

extern "C" void kernel_launch(void* const* d_in, const int* in_sizes, int n_in,
                              void* d_out, int out_size, void* d_ws, size_t ws_size,
                              hipStream_t stream){
  const float* x   = (const float*)d_in[0];
  const float* Wx  = (const float*)d_in[1];
  const float* bx  = (const float*)d_in[2];
  const float* Wmh = (const float*)d_in[3];
  const float* bmh = (const float*)d_in[4];
  const float* Whh = (const float*)d_in[5];
  const float* bhh = (const float*)d_in[6];
  const float* Wg  = (const float*)d_in[7];
  const float* bg  = (const float*)d_in[8];
  float* out = (float*)d_out;
  char* ws = (char*)d_ws;

  const size_t TB = (size_t)T_STEPS*BATCH;
  const size_t PS = TB*HID;

  size_t off=0;
  auto alloc=[&](size_t b){ size_t o=off; off += (b+255)&~(size_t)255; return o; };
  size_t pack_off = alloc(5*PS*2);
  size_t seq_off  = alloc(PS*2);
  size_t wx_off   = alloc((size_t)NLAYER*5*HID*DIM*2);
  size_t wmh_off  = alloc((size_t)NLAYER*HID*HID*2);
  size_t whh_off  = alloc((size_t)NLAYER*HID*HID*2);
  size_t wg_off   = alloc((size_t)NLAYER*3*HID*HID*2);
  size_t whhp_off = alloc((size_t)NLAYER*HID*HID*2);
  size_t whhg_off = alloc((size_t)3*HID*HID*2);
  size_t bias2_off= alloc((size_t)3*HID*4);
  size_t zeros_off= alloc(4096);
  size_t h_off    = alloc((size_t)2*BATCH*HID*2);   // parity double buffer
  size_t m_off    = alloc((size_t)2*BATCH*HID*2);   // parity double buffer
  size_t c_off    = alloc((size_t)BATCH*HID*4);
  size_t flag_off = alloc(32768);
  (void)ws_size;

  u16* pack_p = (u16*)(ws+pack_off);
  u16* seq_p  = (u16*)(ws+seq_off);
  u16* wx_p   = (u16*)(ws+wx_off);
  u16* wmh_p  = (u16*)(ws+wmh_off);
  u16* whh_p  = (u16*)(ws+whh_off);
  u16* wg_p   = (u16*)(ws+wg_off);
  u16* whhpl_p= (u16*)(ws+whhp_off);
  u16* whhg_p = (u16*)(ws+whhg_off);
  float* bias2_p = (float*)(ws+bias2_off);
  float* zeros_p = (float*)(ws+zeros_off);
  u16* h_p  = (u16*)(ws+h_off);
  u16* m_p  = (u16*)(ws+m_off);
  float* c_p= (float*)(ws+c_off);
  u32* flags_p= (u32*)(ws+flag_off);

  hipMemsetAsync(h_p, 0, (size_t)2*BATCH*HID*2, stream);
  hipMemsetAsync(flags_p, 0, 32768, stream);
  hipMemsetAsync(zeros_p, 0, 4096, stream);

  cast_f2bf<<<4096,256,0,stream>>>(x, seq_p, T_STEPS*BATCH*DIM/4);
  cast_f2bf<<<2048,256,0,stream>>>(Whh, whhpl_p, NLAYER*HID*HID/4);

  for(int l=0;l<NLAYER;l++){
    transpose_cast<<<dim3(5*HID/32, DIM/32), dim3(32,8),0,stream>>>(
        Wx + (size_t)l*DIM*5*HID, wx_p + (size_t)l*5*HID*DIM, DIM, 5*HID);
    transpose_cast<<<dim3(HID/32, HID/32), dim3(32,8),0,stream>>>(
        Wmh + (size_t)l*HID*HID, wmh_p + (size_t)l*HID*HID, HID, HID);
    transpose_cast<<<dim3(HID/32, HID/32), dim3(32,8),0,stream>>>(
        Whh + (size_t)l*HID*HID, whh_p + (size_t)l*HID*HID, HID, HID);
    transpose_cast<<<dim3(3*HID/32, HID/32), dim3(32,8),0,stream>>>(
        Wg + (size_t)l*HID*3*HID, wg_p + (size_t)l*3*HID*HID, HID, 3*HID);
  }

  float* seq_out_f32 = out;
  float* hn_out = out + PS;
  float* cn_out = hn_out + (size_t)NLAYER*BATCH*HID;

  for(int l=0;l<NLAYER;l++){
    const u16* wg_l = wg_p + (size_t)l*3*HID*HID;
    bias2_kernel<<<768,256,0,stream>>>(wg_l, bhh + (size_t)l*HID, bg + (size_t)l*3*HID, bias2_p);
    gemm_bt<0><<<dim3(HID/128, 3*HID/128),256,0,stream>>>(
        wg_l, whhpl_p + (size_t)l*HID*HID, zeros_p, whhg_p,
        3*HID, HID, HID, nullptr);
    gemm_bt<1><<<dim3(5*HID/128, (int)(TB/128)),256,0,stream>>>(
        seq_p, wx_p+(size_t)l*5*HID*DIM, bx + (size_t)l*5*HID, nullptr,
        (int)TB, 5*HID, DIM, pack_p);
    gemm_bt<2><<<dim3(3*HID/128, (int)(TB/128)),256,0,stream>>>(
        pack_p, wg_l, bias2_p, nullptr,
        (int)TB, 3*HID, HID, pack_p);

    const u16* wm_c = wmh_p + (size_t)l*HID*HID;
    const u16* wh_c = whh_p + (size_t)l*HID*HID;
    const u16* wG_c = whhg_p;
    const float* bmh_l = bmh + (size_t)l*HID;
    const float* bhh_l = bhh + (size_t)l*HID;
    u16* seqbf = (l==0)? seq_p : (u16*)nullptr;
    float* seqf = (l==0)? (float*)nullptr : seq_out_f32;
    float* hn_l = hn_out + (size_t)l*BATCH*HID;
    float* cn_l = cn_out + (size_t)l*BATCH*HID;
    u32* flags_l = flags_p + (size_t)l*2048;
    int is_first = (l==0)?1:0;

    mlstm_rec<<<dim3(64), dim3(256), 0, stream>>>(
        pack_p, wm_c, wh_c, wG_c, bmh_l, bhh_l,
        h_p, c_p, m_p,
        seqbf, seqf, hn_l, cn_l, flags_l, is_first);
  }
}

// Round 20
// 14753.816 us; speedup vs baseline: 1.0756x; 1.0756x over previous
//
#include <hip/hip_runtime.h>

#define T_STEPS 512
#define BATCH 64
#define DIM 1024
#define HID 1024
#define NLAYER 2
#define XP_STEP (64*5*1024)   // packed-xp elements per time step (64 blocks x 5 planes x 1024)
#define MFMA_B16 __builtin_amdgcn_mfma_f32_16x16x32_bf16

typedef __attribute__((ext_vector_type(8))) short bf16x8;
typedef __attribute__((ext_vector_type(4))) float f32x4;
typedef unsigned short u16;
typedef unsigned int u32;
typedef unsigned long long u64;

__device__ inline float bf2f(u16 u){ u32 v=((u32)u)<<16; float f; __builtin_memcpy(&f,&v,4); return f; }
__device__ inline u16 f2bf(float f){ u32 u; __builtin_memcpy(&u,&f,4); u = (u + 0x7fffu + ((u>>16)&1u))>>16; return (u16)u; }
__device__ inline float sigm(float x){ return 1.f/(1.f+__expf(-x)); }

__device__ inline u32 ld_cc(const u32* p){ return __hip_atomic_load(p, __ATOMIC_RELAXED, __HIP_MEMORY_SCOPE_SYSTEM); }
__device__ inline void st_cc(u32* p, u32 v){ __hip_atomic_store(p, v, __ATOMIC_RELAXED, __HIP_MEMORY_SCOPE_SYSTEM); }

// 8 wide coherent loads (512B span), one addr + imm offsets, no wait (caller waits).
__device__ __forceinline__ void ld8_sys(const u16* p, bf16x8* f){
  asm volatile(
    "global_load_dwordx4 %0, %8, off sc0 sc1\n\t"
    "global_load_dwordx4 %1, %8, off offset:64 sc0 sc1\n\t"
    "global_load_dwordx4 %2, %8, off offset:128 sc0 sc1\n\t"
    "global_load_dwordx4 %3, %8, off offset:192 sc0 sc1\n\t"
    "global_load_dwordx4 %4, %8, off offset:256 sc0 sc1\n\t"
    "global_load_dwordx4 %5, %8, off offset:320 sc0 sc1\n\t"
    "global_load_dwordx4 %6, %8, off offset:384 sc0 sc1\n\t"
    "global_load_dwordx4 %7, %8, off offset:448 sc0 sc1"
    : "=&v"(f[0]),"=&v"(f[1]),"=&v"(f[2]),"=&v"(f[3]),
      "=&v"(f[4]),"=&v"(f[5]),"=&v"(f[6]),"=&v"(f[7])
    : "v"(p)
    : "memory");
}
#define WAITV(S) do{ asm volatile("s_waitcnt vmcnt(" S ")" ::: "memory"); __builtin_amdgcn_sched_barrier(0); }while(0)

// Wait until all 16 producers of group GIDX have flag >= THR (cached ballot mask).
// NOTE: a spinning ballot only OVER-drains vmcnt, so counted WAITVs stay safe.
#define WG(FL, THR, GIDX, READY) do{ \
    u64 need_ = 0xFFFFull << ((GIDX)*16); \
    while(((READY) & need_) != need_){ \
      u32 v_ = ld_cc((FL) + (size_t)lane*32); \
      (READY) = __ballot(v_ >= (u32)(THR)); \
    } }while(0)

// ---------------- fp32 -> bf16 cast ----------------
__global__ void cast_f2bf(const float* __restrict__ src, u16* __restrict__ dst, int n4){
  int i = blockIdx.x*blockDim.x + threadIdx.x;
  int stride = gridDim.x*blockDim.x;
  for(; i<n4; i+=stride){
    float4 v = ((const float4*)src)[i];
    ushort4 o; o.x=f2bf(v.x); o.y=f2bf(v.y); o.z=f2bf(v.z); o.w=f2bf(v.w);
    ((ushort4*)dst)[i]=o;
  }
}

// ---------------- transpose + cast: src fp32 [R][C] -> dst bf16 [C][R] ----------------
__global__ void transpose_cast(const float* __restrict__ src, u16* __restrict__ dst, int R, int C){
  __shared__ float tile[32][33];
  int c0 = blockIdx.x*32, r0 = blockIdx.y*32;
  int tx = threadIdx.x, ty = threadIdx.y;
  for(int i=ty;i<32;i+=8) tile[i][tx] = src[(size_t)(r0+i)*C + c0+tx];
  __syncthreads();
  for(int i=ty;i<32;i+=8) dst[(size_t)(c0+i)*R + r0+tx] = f2bf(tile[tx][i]);
}

// ---------------- bias2 = bhh @ Wg + bg ----------------
__global__ void bias2_kernel(const u16* __restrict__ Wg_t, const float* __restrict__ bhh,
                             const float* __restrict__ bg, float* __restrict__ bias2){
  int w = (blockIdx.x*blockDim.x + threadIdx.x)>>6;
  int lane = threadIdx.x&63;
  if(w >= 3*HID) return;
  float s=0.f;
  for(int j=lane;j<HID;j+=64) s += bf2f(Wg_t[(size_t)w*HID + j]) * bhh[j];
  for(int off=32;off;off>>=1) s += __shfl_down(s, off);
  if(lane==0) bias2[w] = s + bg[w];
}

// ---------------- bf16 GEMM: C = A @ Bt^T + bias ----------------
// MODE 0: plain write. MODE 1: packed [t][cj][p][b][16c]. MODE 2: packed += (A from plane 1).
template<int MODE>
__launch_bounds__(256)
__global__ void gemm_bt(const u16* __restrict__ A, const u16* __restrict__ Bt,
                        const float* __restrict__ bias, u16* __restrict__ Cmat,
                        int M, int N, int K, u16* packed){
  __shared__ __align__(16) u16 As[128*32];
  __shared__ __align__(16) u16 Bs[128*32];
  const int tid=threadIdx.x, lane=tid&63, wave=tid>>6;
  const size_t m0 = (size_t)blockIdx.y*128, n0=(size_t)blockIdx.x*128;
  const int wr=wave>>1, wc=wave&1, fr=lane&15, fq=lane>>4;
  f32x4 acc[4][4];
  for(int m=0;m<4;m++) for(int n=0;n<4;n++) acc[m][n]=(f32x4){0.f,0.f,0.f,0.f};
  const int nk = K>>5;
  for(int kt=0;kt<nk;kt++){
    __syncthreads();
    for(int j=0;j<2;j++){
      int c = tid + j*256; int row=c>>2; int ko=(c&3)*8;
      if constexpr (MODE==2){
        size_t g = m0+row; int kc = kt*32+ko;
        size_t addr = (((g>>6)*64 + (size_t)(kc>>4))*5 + 1)*1024 + (g&63)*16 + (kc&15);
        *(int4*)&As[row*32+ko] = *(const int4*)&A[addr];
      } else {
        *(int4*)&As[row*32+ko] = *(const int4*)&A[(m0+row)*K + kt*32+ko];
      }
      *(int4*)&Bs[row*32+ko] = *(const int4*)&Bt[(n0+row)*K + kt*32+ko];
    }
    __syncthreads();
    bf16x8 af[4], bfv[4];
    for(int m=0;m<4;m++) af[m]=*(const bf16x8*)&As[(wr*64+m*16+fr)*32 + fq*8];
    for(int n=0;n<4;n++) bfv[n]=*(const bf16x8*)&Bs[(wc*64+n*16+fr)*32 + fq*8];
    for(int m=0;m<4;m++)
      for(int n=0;n<4;n++)
        acc[m][n]=MFMA_B16(af[m],bfv[n],acc[m][n],0,0,0);
  }
  for(int n=0;n<4;n++){
    size_t colg = n0 + wc*64+n*16+fr;
    float bv = bias[colg];
    for(int m=0;m<4;m++){
      for(int r=0;r<4;r++){
        size_t rowg = m0 + wr*64+m*16+fq*4+r;
        float v = acc[m][n][r]+bv;
        if constexpr (MODE==0){
          Cmat[rowg*N + colg] = f2bf(v);
        } else if constexpr (MODE==1){
          size_t p = colg>>10, pc = colg&1023;
          size_t t = rowg>>6, b = rowg&63, cj = pc>>4, c = pc&15;
          packed[((t*64+cj)*5 + p)*1024 + b*16 + c] = f2bf(v);
        } else {
          size_t pp = colg>>10, pc = colg&1023;
          size_t t = rowg>>6, b = rowg&63, cj = pc>>4, c = pc&15;
          u16* dst = packed + ((t*64+cj)*5 + (2+pp))*1024 + b*16 + c;
          *dst = f2bf(v + bf2f(*dst));
        }
      }
    }
  }
}

// ---------------- persistent recurrent kernel: barrier-free dataflow ----------------
// 64 blocks x 256 threads. Block cj owns cols [16cj,16cj+16); wave w owns rows
// 16*((w+cj)&3). Per-producer flags (128B stride — line-sparse posts; r19's
// 16B packing serialized same-line write+poll traffic and regressed 8%) +
// 4-group chunked consumption (cached ballot). m/h parity double-buffered.
// xp via global->register scalar loads. seq (HBM) stores AFTER the hflag post.
__launch_bounds__(256, 1)
__global__ void mlstm_rec(const u16* __restrict__ xp_pack,
   const u16* __restrict__ Wmh_t, const u16* __restrict__ Whh_t, const u16* __restrict__ WhhG_t,
   const float* __restrict__ bmh, const float* __restrict__ bhh,
   u16* h_buf, float* c_buf, u16* m_buf,
   u16* seq_bf, float* seq_f32, float* hn, float* cn, u32* flags, int is_first)
{
  __shared__ __align__(16) u16 wlds[64*1024];   // 128 KiB swizzled Whh|WhhG
  const int tid=threadIdx.x, lane=tid&63, wave=tid>>6;
  const int cj = blockIdx.x, cb = cj*16;
  const int rowbase = ((wave + cj) & 3) * 16;
  const int fr=lane&15, fq=lane>>4;
  const int col = cb+fr;
  const u32 a_off = (u32)(rowbase+fr)*HID + fq*8;
  const size_t w_off = (size_t)col*HID + fq*8;
  const u32 swz = ((u32)(fr&7))<<4;
  const int grot = cj&3;
  const int G0=(0+grot)&3, G1=(1+grot)&3, G2=(2+grot)&3, G3=(3+grot)&3;
  u32* mfl = flags;            // mflag[p] at +p*32
  u32* hfl = flags + 2048;     // hflag[p] at +2048+p*32
  const size_t BH = (size_t)BATCH*HID;

  // ---- stage Whh|WhhG into swizzled LDS (once): 8192 x 16B chunks
  for(int it=0; it<32; ++it){
    int chunk = it*256 + tid;
    int cl = chunk >> 7;
    int kb = (chunk & 127) * 16;
    const u16* src;
    if(cl < 16) src = Whh_t + (size_t)(cb+cl)*HID;
    else { int g=(cl-16)>>4, j=cl&15; src = WhhG_t + (size_t)(g*HID + cb + j)*HID; }
    u32 dst = ((u32)cl*2048 + (u32)kb) ^ (((u32)cl&7)<<4);
    *(int4*)((char*)wlds + dst) = *(const int4*)((const char*)src + kb);
  }

  // ---- Wmh fragments into regs, PERMUTED so wmh[8g+j] pairs with kt=8*G(g)+j
  bf16x8 wmh[32];
  {
    const int gtab[4] = {G0,G1,G2,G3};
    #pragma unroll
    for(int g=0; g<4; g++){
      int gg = gtab[g];
      #pragma unroll
      for(int j=0;j<8;j++)
        wmh[8*g+j] = *(const bf16x8*)(Wmh_t + w_off + (size_t)(8*gg+j)*32);
    }
  }

  float c_reg[4], h4[4];
  if(is_first){ for(int r=0;r<4;r++) c_reg[r]=0.f; }
  else { for(int r=0;r<4;r++) c_reg[r]=c_buf[(size_t)(rowbase+fq*4+r)*HID+col]; }
  for(int r=0;r<4;r++) h4[r]=0.f;

  const float bmh_c=bmh[col], bhh_c=bhh[col];

  // per-thread xp base for step 0: chunk cj + [p*1024 + (rowbase+fq*4+r)*16 + fr]
  const u16* xb = xp_pack + (size_t)cj*5120 + (size_t)(rowbase+fq*4)*16 + fr;
  u32 xmi_c[4];
  #pragma unroll
  for(int r=0;r<4;r++) xmi_c[r] = xb[r*16];

  __syncthreads();

  #define MFMA8A(H, W0) do{ \
    a0=MFMA_B16((H)[0],wmh[(W0)+0],a0,0,0,0); a1=MFMA_B16((H)[1],wmh[(W0)+1],a1,0,0,0); \
    a0=MFMA_B16((H)[2],wmh[(W0)+2],a0,0,0,0); a1=MFMA_B16((H)[3],wmh[(W0)+3],a1,0,0,0); \
    a0=MFMA_B16((H)[4],wmh[(W0)+4],a0,0,0,0); a1=MFMA_B16((H)[5],wmh[(W0)+5],a1,0,0,0); \
    a0=MFMA_B16((H)[6],wmh[(W0)+6],a0,0,0,0); a1=MFMA_B16((H)[7],wmh[(W0)+7],a1,0,0,0); \
  }while(0)

  #define MFMA8B(MF, GG) do{ \
    _Pragma("unroll") \
    for(int j=0;j<8;j++){ \
      u32 kb = ((u32)(GG)*8u + (u32)j)*64u + (u32)fq*16u; \
      bf16x8 w0=*(const bf16x8*)(wb + ((((u32)(   fr))*2048 + kb) ^ swz)); \
      bf16x8 w1=*(const bf16x8*)(wb + ((((u32)(16+fr))*2048 + kb) ^ swz)); \
      bf16x8 w2=*(const bf16x8*)(wb + ((((u32)(32+fr))*2048 + kb) ^ swz)); \
      bf16x8 w3=*(const bf16x8*)(wb + ((((u32)(48+fr))*2048 + kb) ^ swz)); \
      ag =MFMA_B16((MF)[j],w0,ag ,0,0,0); aiv=MFMA_B16((MF)[j],w1,aiv,0,0,0); \
      aov=MFMA_B16((MF)[j],w2,aov,0,0,0); afv=MFMA_B16((MF)[j],w3,afv,0,0,0); \
    } }while(0)

  const char* wb = (const char*)wlds;

  for(int t=0;t<T_STEPS;t++){
    // ================= Stage A: m = xmi * (h @ Wmh + bmh) =================
    const u16* h_r = h_buf + (size_t)(t&1)*BH + a_off;
    u64 hready = 0;
    bf16x8 hA[8], hB[8];
    f32x4 a0={0.f,0.f,0.f,0.f}, a1={0.f,0.f,0.f,0.f};
    WG(hfl, t, G0, hready); ld8_sys(h_r + G0*256, hA);
    WG(hfl, t, G1, hready); ld8_sys(h_r + G1*256, hB);
    WAITV("8");  MFMA8A(hA, 0);
    WG(hfl, t, G2, hready); ld8_sys(h_r + G2*256, hA);
    WAITV("8");  MFMA8A(hB, 8);
    WG(hfl, t, G3, hready); ld8_sys(h_r + G3*256, hB);
    WAITV("8");  MFMA8A(hA, 16);
    WAITV("0");  MFMA8A(hB, 24);
    {
      u16* m_w = m_buf + (size_t)(t&1)*BH;
      #pragma unroll
      for(int r=0;r<4;r++){
        int b = rowbase+fq*4+r;
        float xmiv = bf2f((u16)xmi_c[r]);
        u32 my=(u32)f2bf(xmiv*(a0[r]+a1[r]+bmh_c));
        u32 ot=(u32)__shfl_xor((int)my,1);
        if((lane&1)==0) st_cc((u32*)(m_w + (size_t)b*HID + col), my|(ot<<16));
      }
    }
    __syncthreads();            // implicit per-wave vmcnt(0) drains m stores (+prev seq)
    if(tid==0) st_cc(&mfl[(size_t)cj*32], (u32)(t+1));

    // ================= Stage B: [g|i|o|f] = m @ [Whh|WhhG]_lds =================
    const u16* m_r = m_buf + (size_t)(t&1)*BH + a_off;
    u64 mready = 0;
    bf16x8 mA[8], mB[8];
    f32x4 ag={0.f,0.f,0.f,0.f}, aiv={0.f,0.f,0.f,0.f}, aov={0.f,0.f,0.f,0.f}, afv={0.f,0.f,0.f,0.f};
    WG(mfl, t+1, G0, mready); ld8_sys(m_r + G0*256, mA);
    WG(mfl, t+1, G1, mready); ld8_sys(m_r + G1*256, mB);
    // xp scalar loads: 16 gate values (step t) + 4 xmi (step t+1) — 20 VMEM ops
    const u16* xbn = (t+1<T_STEPS)? (xb+XP_STEP) : xb;
    u32 xhi_[4],xgi_[4],xgo_[4],xgf_[4],xmi_n[4];
    #pragma unroll
    for(int r=0;r<4;r++){ xhi_[r]=xb[1024+r*16]; xgi_[r]=xb[2048+r*16];
                          xgo_[r]=xb[3072+r*16]; xgf_[r]=xb[4096+r*16]; }
    #pragma unroll
    for(int r=0;r<4;r++){ xmi_n[r]=xbn[r*16]; }
    // queue: G0(8) G1(8) scalars(20) | +G2(8) | +G3(8)
    WAITV("28"); MFMA8B(mA, G0);                      // drains G0
    WG(mfl, t+1, G2, mready); ld8_sys(m_r + G2*256, mA);
    WAITV("28"); MFMA8B(mB, G1);                      // drains G1
    WG(mfl, t+1, G3, mready); ld8_sys(m_r + G3*256, mB);
    WAITV("8");  MFMA8B(mA, G2);                      // drains scalars + G2
    WAITV("0");  MFMA8B(mB, G3);                      // drains G3
    // gates + state update; h stores FIRST (gate the flag), seq AFTER the post
    {
      u16* h_w = h_buf + (size_t)((t+1)&1)*BH;
      #pragma unroll
      for(int r=0;r<4;r++){
        int b=rowbase+fq*4+r;
        float g  = ag[r]+bhh_c+bf2f((u16)xhi_[r]);
        float iv = sigm(aiv[r]+bf2f((u16)xgi_[r]));
        float ov = sigm(aov[r]+bf2f((u16)xgo_[r]));
        float fv = sigm(afv[r]+bf2f((u16)xgf_[r]));
        c_reg[r]=fv*c_reg[r]+iv*tanhf(g);
        h4[r]=tanhf(c_reg[r])*ov;
        u32 my=(u32)f2bf(h4[r]);
        u32 ot=(u32)__shfl_xor((int)my,1);
        if((lane&1)==0) st_cc((u32*)(h_w + (size_t)b*HID + col), my|(ot<<16));
      }
    }
    __syncthreads();            // implicit per-wave vmcnt(0) drains h stores ONLY
    if(tid==0) st_cc(&hfl[(size_t)cj*32], (u32)(t+1));
    // seq output stores AFTER the flag post — retire during next stage A
    {
      const size_t tb=(size_t)t*BH;
      #pragma unroll
      for(int r=0;r<4;r++){
        int b=rowbase+fq*4+r;
        if(seq_bf) seq_bf[tb+(size_t)b*HID+col]=f2bf(h4[r]);
        else       seq_f32[tb+(size_t)b*HID+col]=h4[r];
      }
    }
    #pragma unroll
    for(int r=0;r<4;r++) xmi_c[r]=xmi_n[r];
    xb = xbn;
  }
  // epilogue: hn, cn (seq written every step)
  for(int r=0;r<4;r++){
    int row=rowbase+fq*4+r;
    hn[(size_t)row*HID+col]=h4[r];
    cn[(size_t)row*HID+col]=c_reg[r];
    if(is_first) c_buf[(size_t)row*HID+col]=c_reg[r];
  }
}

extern "C" void kernel_launch(void* const* d_in, const int* in_sizes, int n_in,
                              void* d_out, int out_size, void* d_ws, size_t ws_size,
                              hipStream_t stream){
  const float* x   = (const float*)d_in[0];
  const float* Wx  = (const float*)d_in[1];
  const float* bx  = (const float*)d_in[2];
  const float* Wmh = (const float*)d_in[3];
  const float* bmh = (const float*)d_in[4];
  const float* Whh = (const float*)d_in[5];
  const float* bhh = (const float*)d_in[6];
  const float* Wg  = (const float*)d_in[7];
  const float* bg  = (const float*)d_in[8];
  float* out = (float*)d_out;
  char* ws = (char*)d_ws;

  const size_t TB = (size_t)T_STEPS*BATCH;
  const size_t PS = TB*HID;

  size_t off=0;
  auto alloc=[&](size_t b){ size_t o=off; off += (b+255)&~(size_t)255; return o; };
  size_t pack_off = alloc(5*PS*2);
  size_t seq_off  = alloc(PS*2);
  size_t wx_off   = alloc((size_t)NLAYER*5*HID*DIM*2);
  size_t wmh_off  = alloc((size_t)NLAYER*HID*HID*2);
  size_t whh_off  = alloc((size_t)NLAYER*HID*HID*2);
  size_t wg_off   = alloc((size_t)NLAYER*3*HID*HID*2);
  size_t whhp_off = alloc((size_t)NLAYER*HID*HID*2);
  size_t whhg_off = alloc((size_t)3*HID*HID*2);
  size_t bias2_off= alloc((size_t)3*HID*4);
  size_t zeros_off= alloc(4096);
  size_t h_off    = alloc((size_t)2*BATCH*HID*2);   // parity double buffer
  size_t m_off    = alloc((size_t)2*BATCH*HID*2);   // parity double buffer
  size_t c_off    = alloc((size_t)BATCH*HID*4);
  size_t flag_off = alloc(32768);
  (void)ws_size;

  u16* pack_p = (u16*)(ws+pack_off);
  u16* seq_p  = (u16*)(ws+seq_off);
  u16* wx_p   = (u16*)(ws+wx_off);
  u16* wmh_p  = (u16*)(ws+wmh_off);
  u16* whh_p  = (u16*)(ws+whh_off);
  u16* wg_p   = (u16*)(ws+wg_off);
  u16* whhpl_p= (u16*)(ws+whhp_off);
  u16* whhg_p = (u16*)(ws+whhg_off);
  float* bias2_p = (float*)(ws+bias2_off);
  float* zeros_p = (float*)(ws+zeros_off);
  u16* h_p  = (u16*)(ws+h_off);
  u16* m_p  = (u16*)(ws+m_off);
  float* c_p= (float*)(ws+c_off);
  u32* flags_p= (u32*)(ws+flag_off);

  hipMemsetAsync(h_p, 0, (size_t)2*BATCH*HID*2, stream);
  hipMemsetAsync(flags_p, 0, 32768, stream);
  hipMemsetAsync(zeros_p, 0, 4096, stream);

  cast_f2bf<<<4096,256,0,stream>>>(x, seq_p, T_STEPS*BATCH*DIM/4);
  cast_f2bf<<<2048,256,0,stream>>>(Whh, whhpl_p, NLAYER*HID*HID/4);

  for(int l=0;l<NLAYER;l++){
    transpose_cast<<<dim3(5*HID/32, DIM/32), dim3(32,8),0,stream>>>(
        Wx + (size_t)l*DIM*5*HID, wx_p + (size_t)l*5*HID*DIM, DIM, 5*HID);
    transpose_cast<<<dim3(HID/32, HID/32), dim3(32,8),0,stream>>>(
        Wmh + (size_t)l*HID*HID, wmh_p + (size_t)l*HID*HID, HID, HID);
    transpose_cast<<<dim3(HID/32, HID/32), dim3(32,8),0,stream>>>(
        Whh + (size_t)l*HID*HID, whh_p + (size_t)l*HID*HID, HID, HID);
    transpose_cast<<<dim3(3*HID/32, HID/32), dim3(32,8),0,stream>>>(
        Wg + (size_t)l*HID*3*HID, wg_p + (size_t)l*3*HID*HID, HID, 3*HID);
  }

  float* seq_out_f32 = out;
  float* hn_out = out + PS;
  float* cn_out = hn_out + (size_t)NLAYER*BATCH*HID;

  for(int l=0;l<NLAYER;l++){
    const u16* wg_l = wg_p + (size_t)l*3*HID*HID;
    bias2_kernel<<<768,256,0,stream>>>(wg_l, bhh + (size_t)l*HID, bg + (size_t)l*3*HID, bias2_p);
    gemm_bt<0><<<dim3(HID/128, 3*HID/128),256,0,stream>>>(
        wg_l, whhpl_p + (size_t)l*HID*HID, zeros_p, whhg_p,
        3*HID, HID, HID, nullptr);
    gemm_bt<1><<<dim3(5*HID/128, (int)(TB/128)),256,0,stream>>>(
        seq_p, wx_p+(size_t)l*5*HID*DIM, bx + (size_t)l*5*HID, nullptr,
        (int)TB, 5*HID, DIM, pack_p);
    gemm_bt<2><<<dim3(3*HID/128, (int)(TB/128)),256,0,stream>>>(
        pack_p, wg_l, bias2_p, nullptr,
        (int)TB, 3*HID, HID, pack_p);

    const u16* wm_c = wmh_p + (size_t)l*HID*HID;
    const u16* wh_c = whh_p + (size_t)l*HID*HID;
    const u16* wG_c = whhg_p;
    const float* bmh_l = bmh + (size_t)l*HID;
    const float* bhh_l = bhh + (size_t)l*HID;
    u16* seqbf = (l==0)? seq_p : (u16*)nullptr;
    float* seqf = (l==0)? (float*)nullptr : seq_out_f32;
    float* hn_l = hn_out + (size_t)l*BATCH*HID;
    float* cn_l = cn_out + (size_t)l*BATCH*HID;
    u32* flags_l = flags_p + (size_t)l*4096;
    int is_first = (l==0)?1:0;

    mlstm_rec<<<dim3(64), dim3(256), 0, stream>>>(
        pack_p, wm_c, wh_c, wG_c, bmh_l, bhh_l,
        h_p, c_p, m_p,
        seqbf, seqf, hn_l, cn_l, flags_l, is_first);
  }
}